// Round 9
// baseline (346.562 us; speedup 1.0000x reference)
//
#include <hip/hip_runtime.h>

// MultiHeadAttention: BS=4, N=2048, D=512, H=8, DK=64. fp32 in/out, bf16 MFMA compute.
// Round 9: attn v6 "wave-owns-keys": Q-frags in registers (loop-invariant), each wave
// reads only its 32-key K/V slice from LDS (4x fewer frag reads), P buffer padded to
// 72B rows (conflict-free), l via all-ones MFMA, 4-round LDS O-merge.
// GEMMs/prep unchanged from R8 (isolation + they surface in top-5 once attn shrinks).

#define BS_    4
#define NSEQ   2048
#define DMODEL 512
#define NH     8
#define DKH    64
#define MROWS  (BS_ * NSEQ)   // 8192
#define NW32   (NSEQ / 32)    // 64 mask dwords per row
#define XN     ((size_t)MROWS * DMODEL)
#define WN     ((size_t)DMODEL * DMODEL)

typedef unsigned short ushort_t;
typedef __attribute__((ext_vector_type(8))) short short8;   // 8 bf16 (4 VGPRs)
typedef __attribute__((ext_vector_type(4))) float floatx4;  // 4 fp32 acc

__device__ __forceinline__ ushort_t f2bf(float f) {   // round-half-up
    unsigned int x = __builtin_bit_cast(unsigned int, f);
    return (ushort_t)((x + 0x8000u) >> 16);
}
__device__ __forceinline__ unsigned int pack2bf(float lo, float hi) {
    const unsigned int a = __builtin_bit_cast(unsigned int, lo) + 0x8000u;
    const unsigned int b = __builtin_bit_cast(unsigned int, hi) + 0x8000u;
    return __builtin_amdgcn_perm(b, a, 0x07060302u);  // {hi16(b), hi16(a)}
}
__device__ __forceinline__ floatx4 mfma_bf16(short8 a, short8 b, floatx4 c) {
    return __builtin_amdgcn_mfma_f32_16x16x32_bf16(a, b, c, 0, 0, 0);
}
__device__ __forceinline__ void gld16(const ushort_t* g, ushort_t* l) {
    __builtin_amdgcn_global_load_lds(
        (const __attribute__((address_space(1))) unsigned int*)g,
        (__attribute__((address_space(3))) unsigned int*)l, 16, 0, 0);
}

// ---------------- fused prep: QKV/W converts + mask bit-pack ----------------
__global__ __launch_bounds__(256) void prep_kernel(const float* __restrict__ Q,
                                                   const float* __restrict__ K,
                                                   const float* __restrict__ V,
                                                   const float* __restrict__ WQ,
                                                   const float* __restrict__ WK,
                                                   const float* __restrict__ WV,
                                                   const float* __restrict__ WO,
                                                   const float* __restrict__ am,
                                                   ushort_t* __restrict__ Xbf,
                                                   ushort_t* __restrict__ Wbf,
                                                   unsigned int* __restrict__ pm) {
    const int bx  = blockIdx.x;
    const int tid = threadIdx.x;
    if (bx < 12288) {
        const int seg = bx >> 12;
        const int i = (bx & 4095) * 256 + tid;
        const float* src = (seg == 0) ? Q : (seg == 1) ? K : V;
        const float4 v = ((const float4*)src)[i];
        ushort4 o;
        o.x = f2bf(v.x); o.y = f2bf(v.y); o.z = f2bf(v.z); o.w = f2bf(v.w);
        ((ushort4*)(Xbf + (size_t)seg * XN))[i] = o;
    } else if (bx < 13312) {
        const int b2 = bx - 12288;
        const int seg = b2 >> 8;
        const int i = (b2 & 255) * 256 + tid;
        const float* src = (seg == 0) ? WQ : (seg == 1) ? WK : (seg == 2) ? WV : WO;
        const float4 v = ((const float4*)src)[i];
        ushort4 o;
        o.x = f2bf(v.x); o.y = f2bf(v.y); o.z = f2bf(v.z); o.w = f2bf(v.w);
        ((ushort4*)(Wbf + (size_t)seg * WN))[i] = o;
    } else {
        const int gid = (bx - 13312) * 256 + tid;
        const float v = am[gid];
        const unsigned long long m = __ballot(v != 0.f);
        if ((tid & 63) == 0) {
            uint2 w; w.x = (unsigned int)m; w.y = (unsigned int)(m >> 32);
            *(uint2*)&pm[gid >> 5] = w;
        }
    }
}

// ---------------- GEMM v3 core: 64x128 tile, BK=64, both staged ----------------
#define GEMM_V3_LOOP(X_, W_)                                                          \
    floatx4 acc[2][4];                                                                \
    _Pragma("unroll") for (int t = 0; t < 2; ++t)                                     \
        _Pragma("unroll") for (int u = 0; u < 4; ++u)                                 \
            acc[t][u] = (floatx4){0.f, 0.f, 0.f, 0.f};                                \
    for (int k0 = 0; k0 < DMODEL; k0 += 64) {                                         \
        _Pragma("unroll") for (int i = 0; i < 2; ++i) {                               \
            const int ca = wave * 2 + i, mg = ca >> 1, kc = ca & 1;                   \
            gld16(X_ + (size_t)(m0 + mg * 16 + r4) * DMODEL + k0 + kc * 32 + p4 * 8,  \
                  &As[ca * 512]);                                                     \
        }                                                                             \
        _Pragma("unroll") for (int i = 0; i < 4; ++i) {                               \
            const int cb = wave * 4 + i, ng = cb >> 1, kc = cb & 1;                   \
            gld16(W_ + (size_t)(n0 + ng * 16 + r4) * DMODEL + k0 + kc * 32 + p4 * 8,  \
                  &Bs[cb * 512]);                                                     \
        }                                                                             \
        __syncthreads();                                                              \
        _Pragma("unroll") for (int kc = 0; kc < 2; ++kc) {                            \
            short8 a[2], bfr[4];                                                      \
            _Pragma("unroll") for (int t = 0; t < 2; ++t)                             \
                a[t] = *(const short8*)&As[((wr * 2 + t) * 2 + kc) * 512 +            \
                                           l16 * 32 + quad * 8];                      \
            _Pragma("unroll") for (int u = 0; u < 4; ++u)                             \
                bfr[u] = *(const short8*)&Bs[((wc * 4 + u) * 2 + kc) * 512 +          \
                                             l16 * 32 + quad * 8];                    \
            _Pragma("unroll") for (int t = 0; t < 2; ++t)                             \
                _Pragma("unroll") for (int u = 0; u < 4; ++u)                         \
                    acc[t][u] = mfma_bf16(a[t], bfr[u], acc[t][u]);                   \
        }                                                                             \
        __syncthreads();                                                              \
    }

// ---------------- fused projection GEMM (Q/K/V via blockIdx.z) ----------------
__global__ __launch_bounds__(256) void gemm_proj(const ushort_t* __restrict__ Xall,
                                                 const ushort_t* __restrict__ Wall,
                                                 const float* __restrict__ qmas,
                                                 const float* __restrict__ kmas,
                                                 ushort_t* __restrict__ Qh,
                                                 ushort_t* __restrict__ Kh,
                                                 ushort_t* __restrict__ Vt) {
    __shared__ ushort_t As[8 * 512];    // 8 KB
    __shared__ ushort_t Bs[16 * 512];   // 16 KB
    const int z = blockIdx.z;
    const ushort_t* X  = Xall + (size_t)z * XN;
    const ushort_t* Wb = Wall + (size_t)z * WN;
    const float* rowmask = (z == 0) ? qmas : kmas;

    const int tid  = threadIdx.x;
    const int wave = tid >> 6;
    const int lane = tid & 63;
    const int l16  = lane & 15;
    const int quad = lane >> 4;
    const int wr   = wave >> 1;
    const int wc   = wave & 1;
    const int m0   = blockIdx.x * 64;
    const int n0   = blockIdx.y * 128;
    const int r4   = lane >> 2;
    const int p4   = lane & 3;

    GEMM_V3_LOOP(X, Wb)

    float rm[2][4];
#pragma unroll
    for (int t = 0; t < 2; ++t)
#pragma unroll
        for (int r = 0; r < 4; ++r)
            rm[t][r] = rowmask[m0 + wr * 32 + t * 16 + quad * 4 + r];

    const int bb    = m0 >> 11;
    const int nbase = (m0 & (NSEQ - 1)) + wr * 32;
    const int hh    = (n0 >> 6) + wc;   // this wave's 64-col strip = one head

    if (z < 2) {
        ushort_t* dst = (z == 0) ? Qh : Kh;
#pragma unroll
        for (int t = 0; t < 2; ++t)
#pragma unroll
            for (int u = 0; u < 4; ++u)
#pragma unroll
                for (int r = 0; r < 4; ++r) {
                    const int n = nbase + t * 16 + quad * 4 + r;
                    dst[((size_t)(bb * NH + hh) * NSEQ + n) * DKH + u * 16 + l16] =
                        f2bf(acc[t][u][r] * rm[t][r]);
                }
    } else {
#pragma unroll
        for (int t = 0; t < 2; ++t)
#pragma unroll
            for (int u = 0; u < 4; ++u) {
                ushort4 pk;
                pk.x = f2bf(acc[t][u][0] * rm[t][0]);
                pk.y = f2bf(acc[t][u][1] * rm[t][1]);
                pk.z = f2bf(acc[t][u][2] * rm[t][2]);
                pk.w = f2bf(acc[t][u][3] * rm[t][3]);
                const int n = nbase + t * 16 + quad * 4;
                *(ushort4*)(Vt + ((size_t)(bb * NH + hh) * DKH + u * 16 + l16) * NSEQ + n) = pk;
            }
    }
}

// ---------------- output GEMM ----------------
__global__ __launch_bounds__(256) void gemm_out(const ushort_t* __restrict__ X,
                                                const ushort_t* __restrict__ Wb,
                                                const float* __restrict__ rowmask,
                                                float* __restrict__ dst) {
    __shared__ ushort_t As[8 * 512];
    __shared__ ushort_t Bs[16 * 512];
    const int tid  = threadIdx.x;
    const int wave = tid >> 6;
    const int lane = tid & 63;
    const int l16  = lane & 15;
    const int quad = lane >> 4;
    const int wr   = wave >> 1;
    const int wc   = wave & 1;
    const int m0   = blockIdx.x * 64;
    const int n0   = blockIdx.y * 128;
    const int r4   = lane >> 2;
    const int p4   = lane & 3;

    GEMM_V3_LOOP(X, Wb)

#pragma unroll
    for (int t = 0; t < 2; ++t)
#pragma unroll
        for (int r = 0; r < 4; ++r) {
            const int m = m0 + wr * 32 + t * 16 + quad * 4 + r;
            const float rm = rowmask[m];
#pragma unroll
            for (int u = 0; u < 4; ++u)
                dst[(size_t)m * DMODEL + n0 + wc * 64 + u * 16 + l16] =
                    acc[t][u][r] * rm;
        }
}

// ---------------- flash attention v6: wave-owns-keys ----------------
// Block = 64 q-rows x 128-key tiles; wave w owns keys [w*32, w*32+32) of each tile.
// Q-frags in registers (loop-invariant). S' = mfma(A=K, B=Q) -> C[key][q].
// P buffer padded (72B rows, conflict-free). l via all-ones-A MFMA.
// Epilogue: 4-round LDS merge of the 4 per-wave O-partials.
__global__ __launch_bounds__(256, 3) void attn_kernel(const ushort_t* __restrict__ Qh,
                                                      const ushort_t* __restrict__ Kh,
                                                      const ushort_t* __restrict__ Vt,
                                                      const unsigned int* __restrict__ pmask,
                                                      const float* __restrict__ kmas,
                                                      ushort_t* __restrict__ y) {
    __shared__ __align__(16) unsigned char smem[16384 + 16384 + 4 * 4608 + 256];
    ushort_t* Ks  = (ushort_t*)smem;              // [2 kc][128 key][32 c]   16 KB
    ushort_t* Vs  = (ushort_t*)(smem + 16384);    // [4 kf][64 c][32 key]    16 KB
    ushort_t* Pw4 = (ushort_t*)(smem + 32768);    // [4 w][64 q][36 key-pad] 18 KB
    float*    Ob  = (float*)smem;                 // epilogue: [4 w][16 q][68 c] 17.4 KB
    float*    Lb  = (float*)(smem + 32768 + 4 * 4608);  // [4 w][16 q]

    const int tid  = threadIdx.x;
    const int wave = tid >> 6;
    const int lane = tid & 63;
    const int l16  = lane & 15;
    const int quad = lane >> 4;
    const int r4   = lane >> 2;
    const int p4   = lane & 3;
    const int h    = blockIdx.y;
    const int b    = blockIdx.z;
    const int q0   = blockIdx.x * 64;

    const ushort_t* Kb = Kh + (size_t)(b * NH + h) * NSEQ * DKH;
    const ushort_t* Vb = Vt + (size_t)(b * NH + h) * DKH * NSEQ;
    const unsigned int* Pm = pmask + (size_t)(b * NSEQ + q0) * NW32;
    ushort_t* Pw = Pw4 + wave * (64 * 36);

    // Q-frags: B-operand, loop-invariant: qf[qg][kc] = Q[q0+qg*16+l16][kc*32+quad*8]
    short8 qf[4][2];
#pragma unroll
    for (int qg = 0; qg < 4; ++qg) {
        const ushort_t* Qp =
            Qh + ((size_t)((b * NH + h) * NSEQ) + q0 + qg * 16 + l16) * DKH + quad * 8;
        qf[qg][0] = *(const short8*)Qp;
        qf[qg][1] = *(const short8*)(Qp + 32);
    }

    short8 ones;
#pragma unroll
    for (int i = 0; i < 8; ++i) ones[i] = (short)0x3F80;  // bf16 1.0

    floatx4 accO[4][4];   // [cg][qg]  O^T partial: row=c, col=q
    floatx4 accL[4];      // [qg]      l partial (all rows equal)
#pragma unroll
    for (int cg = 0; cg < 4; ++cg)
#pragma unroll
        for (int qg = 0; qg < 4; ++qg) accO[cg][qg] = (floatx4){0.f, 0.f, 0.f, 0.f};
#pragma unroll
    for (int qg = 0; qg < 4; ++qg) accL[qg] = (floatx4){0.f, 0.f, 0.f, 0.f};

    const float CEXP = 0.18033688011112042f;  // log2(e)/8

    for (int kt = 0; kt < NSEQ / 128; ++kt) {
        const int k0 = kt * 128;

        __syncthreads();   // previous tile's Ks/Vs reads complete (WAR)

        // this lane's mask dword: q-row = l16 (per q-group handled via qg loop? no:
        // S' col=q=l16, so lane's 32 q-key bits: row q = qg*16+l16 -> need per qg!)
        // -> load 4 dwords, one per q-group, all for this wave's 32-key slice.
        unsigned int mw[4];
#pragma unroll
        for (int qg = 0; qg < 4; ++qg)
            mw[qg] = Pm[(size_t)(qg * 16 + l16) * NW32 + kt * 4 + wave];

        // stage K (16 KB) and V (16 KB)
#pragma unroll
        for (int i = 0; i < 4; ++i) {
            const int idx = wave * 4 + i;
            const int kc = idx >> 3, rg = idx & 7;
            gld16(Kb + (size_t)(k0 + rg * 16 + r4) * DKH + kc * 32 + p4 * 8,
                  &Ks[kc * 4096 + rg * 512]);
        }
#pragma unroll
        for (int i = 0; i < 4; ++i) {
            const int idx = wave * 4 + i;
            const int kf = idx >> 2, rg = idx & 3;
            gld16(Vb + (size_t)(rg * 16 + r4) * NSEQ + k0 + kf * 32 + p4 * 8,
                  &Vs[kf * 2048 + rg * 512]);
        }
        __syncthreads();   // tile staged

        // ---- per key-halfslice fr: S' (8 MFMAs) + softmax + P write ----
#pragma unroll
        for (int fr = 0; fr < 2; ++fr) {
            const int krow = wave * 32 + fr * 16 + l16;   // key row in tile
            const short8 ka = *(const short8*)&Ks[(krow) * 32 + quad * 8];
            const short8 kb = *(const short8*)&Ks[4096 + (krow) * 32 + quad * 8];
            floatx4 S[4];
#pragma unroll
            for (int qg = 0; qg < 4; ++qg) {
                floatx4 s = {0.f, 0.f, 0.f, 0.f};
                s = mfma_bf16(ka, qf[qg][0], s);
                s = mfma_bf16(kb, qf[qg][1], s);
                S[qg] = s;
            }
            // C layout: col=l16=q-in-group, row=quad*4+r = key offset (+16*fr)
#pragma unroll
            for (int qg = 0; qg < 4; ++qg) {
                float p[4];
#pragma unroll
                for (int r = 0; r < 4; ++r) {
                    const unsigned int bit =
                        (mw[qg] >> (fr * 16 + quad * 4 + r)) & 1u;
                    const float e = exp2f(S[qg][r] * CEXP);
                    p[r] = bit ? e : 0.f;
                }
                uint2 w;
                w.x = pack2bf(p[0], p[1]);
                w.y = pack2bf(p[2], p[3]);
                // P[q][key]: q = qg*16+l16, keys fr*16+quad*4 .. +3 (4 adjacent)
                *(uint2*)&Pw[(qg * 16 + l16) * 36 + fr * 16 + quad * 4] = w;
            }
        }

        __builtin_amdgcn_wave_barrier();  // Pw W->R order (wave-private, in-order DS)

        // P B-frags: pf[qg] = P[q=qg*16+l16][key quad*8 .. +7]
        short8 pf[4];
#pragma unroll
        for (int qg = 0; qg < 4; ++qg)
            pf[qg] = *(const short8*)&Pw[(qg * 16 + l16) * 36 + quad * 8];

        // O^T += V^T . P  (16 MFMAs) + l via ones-A (4 MFMAs)
#pragma unroll
        for (int cg = 0; cg < 4; ++cg) {
            const short8 vf = *(const short8*)&Vs[wave * 2048 + (cg * 16 + l16) * 32 + quad * 8];
#pragma unroll
            for (int qg = 0; qg < 4; ++qg)
                accO[cg][qg] = mfma_bf16(vf, pf[qg], accO[cg][qg]);
        }
#pragma unroll
        for (int qg = 0; qg < 4; ++qg)
            accL[qg] = mfma_bf16(ones, pf[qg], accL[qg]);
    }

    // ---- epilogue: 4 rounds (one q-group per round), 4-way merge in LDS ----
    for (int rr = 0; rr < 4; ++rr) {
        __syncthreads();   // prior round reads / loop LDS reads complete
        // write this wave's partial for q-group rr: O^T[c][q=rr*16+l16]
#pragma unroll
        for (int cg = 0; cg < 4; ++cg)
            *(float4*)&Ob[wave * 1088 + l16 * 68 + cg * 16 + quad * 4] =
                (float4){accO[cg][rr][0], accO[cg][rr][1],
                         accO[cg][rr][2], accO[cg][rr][3]};
        if (quad == 0) Lb[wave * 16 + l16] = accL[rr][0];
        __syncthreads();
        // reduce: thread t -> q=t>>4 (0..15), c-base=(t&15)*4
        const int q  = tid >> 4;
        const int cb = (tid & 15) * 4;
        float4 s = {0.f, 0.f, 0.f, 0.f};
#pragma unroll
        for (int w = 0; w < 4; ++w) {
            const float4 v = *(const float4*)&Ob[w * 1088 + q * 68 + cb];
            s.x += v.x; s.y += v.y; s.z += v.z; s.w += v.w;
        }
        const float l = Lb[q] + Lb[16 + q] + Lb[32 + q] + Lb[48 + q];
        const int qa = q0 + rr * 16 + q;
        const float scale = kmas[b * NSEQ + qa] / l;
        ushort4 o;
        o.x = f2bf(s.x * scale);
        o.y = f2bf(s.y * scale);
        o.z = f2bf(s.z * scale);
        o.w = f2bf(s.w * scale);
        *(ushort4*)&y[(size_t)(b * NSEQ + qa) * DMODEL + h * DKH + cb] = o;
    }
}

extern "C" void kernel_launch(void* const* d_in, const int* in_sizes, int n_in,
                              void* d_out, int out_size, void* d_ws, size_t ws_size,
                              hipStream_t stream) {
    (void)in_sizes; (void)n_in; (void)out_size; (void)ws_size;
    const float* Q  = (const float*)d_in[0];
    const float* K  = (const float*)d_in[1];
    const float* V  = (const float*)d_in[2];
    const float* qm = (const float*)d_in[3];
    const float* km = (const float*)d_in[4];
    const float* am = (const float*)d_in[5];
    const float* WQ = (const float*)d_in[6];
    const float* WK = (const float*)d_in[7];
    const float* WV = (const float*)d_in[8];
    const float* WO = (const float*)d_in[9];

    ushort_t* Xbf = (ushort_t*)d_ws;                 // Q,K,V bf16: 3*XN
    ushort_t* Wbf = Xbf + 3 * XN;                    // WQ,WK,WV,WO bf16: 4*WN
    ushort_t* WOb = Wbf + 3 * WN;
    ushort_t* Qh  = Wbf + 4 * WN;
    ushort_t* Kh  = Qh + XN;
    ushort_t* Vt  = Kh + XN;
    ushort_t* y   = Vt + XN;
    unsigned int* pm = (unsigned int*)(y + XN);      // 2 MB bit-packed mask
    float* out = (float*)d_out;

    hipLaunchKernelGGL(prep_kernel, dim3(78848), dim3(256), 0, stream,
                       Q, K, V, WQ, WK, WV, WO, am, Xbf, Wbf, pm);

    hipLaunchKernelGGL(gemm_proj, dim3(MROWS / 64, DMODEL / 128, 3), dim3(256), 0, stream,
                       Xbf, Wbf, qm, km, Qh, Kh, Vt);

    hipLaunchKernelGGL(attn_kernel, dim3(NSEQ / 64, NH, BS_), dim3(256), 0, stream,
                       Qh, Kh, Vt, pm, km, y);

    hipLaunchKernelGGL(gemm_out, dim3(MROWS / 64, DMODEL / 128), dim3(256), 0, stream,
                       y, WOb, km, out);
}